// Round 6
// baseline (1550.011 us; speedup 1.0000x reference)
//
#include <hip/hip_runtime.h>
#include <math.h>

// ---------------- problem constants ----------------
#define NTRK   1500
#define BSZ    64
#define NTOT   (NTRK*BSZ)        // 96000 tracks
#define LHID   128
#define TSTEPS 6
#define HID    256

#define TPB    512               // 8 waves: (unit-group 0..3) x (track-half 0..1)
#define MTRK   64                // tracks per block
#define NBLK   (NTOT/MTRK)       // 1500 blocks

// ws layout (in shorts / bf16 elements)
#define WHH0_OFF 0
#define WIH1_OFF 65536
#define WHH1_OFF 131072
#define W0B_OFF  196608          // mlp w0 cols 3..130 -> [256][128]
#define W1B_OFF  229376          // mlp w1 [256][256]
#define WS_SHORTS 294912         // 576 KiB

// output layout (flat fp32, return order)
#define OUT1_OFF ((size_t)NTOT*HID)
#define OUT2_OFF (OUT1_OFF + (size_t)NTOT*(HID/2))
#define OUT3_OFF (OUT2_OFF + (size_t)NTOT)
#define OUT4_OFF (OUT3_OFF + (size_t)NTOT)

typedef __bf16 bf16x8 __attribute__((ext_vector_type(8)));
typedef float  f32x4  __attribute__((ext_vector_type(4)));

__device__ __forceinline__ unsigned short f2b(float f) {
    union { float f; unsigned u; } v; v.f = f;
    return (unsigned short)((v.u + 0x7FFF + ((v.u >> 16) & 1)) >> 16);
}
__device__ __forceinline__ float sigf(float x) { return 1.0f / (1.0f + __expf(-x)); }
__device__ __forceinline__ float tanhfast(float x) {
    float e = __expf(2.0f * x);
    return (e - 1.0f) / (e + 1.0f);
}

// ---------------- prep: fp32 -> bf16 weight repack into ws ----------------
__global__ __launch_bounds__(256)
void prep_kernel(const float* __restrict__ Whh0, const float* __restrict__ Wih1,
                 const float* __restrict__ Whh1, const float* __restrict__ w0,
                 const float* __restrict__ w1, unsigned short* __restrict__ ws)
{
    int i = blockIdx.x * 256 + threadIdx.x;
    if (i < 65536)            ws[WHH0_OFF + i] = f2b(Whh0[i]);
    else if (i < 131072)      ws[WIH1_OFF + (i - 65536)]  = f2b(Wih1[i - 65536]);
    else if (i < 196608)      ws[WHH1_OFF + (i - 131072)] = f2b(Whh1[i - 131072]);
    else if (i < 229376) { int j = i - 196608; int n = j >> 7, k = j & 127;
                           ws[W0B_OFF + j] = f2b(w0[n * 131 + 3 + k]); }
    else if (i < WS_SHORTS)   ws[W1B_OFF + (i - 229376)]  = f2b(w1[i - 229376]);
}

// A-layout LDS address (in shorts), 64-track buffer, K=128 (4 k-tiles):
__device__ __forceinline__ int aoff4(int m, int k) {
    return (((m >> 4) * 4 + (k >> 5)) * 64 + ((k >> 3) & 3) * 16 + (m & 15)) * 8 + (k & 7);
}

// acc[mt][ti] += A(hA, m-tiles mtb..mtb+1) · B(Wb rows rowb[ti]) over K=128
__device__ __forceinline__ void accum8(f32x4 (&acc)[2][8],
                                       const unsigned short* __restrict__ Wb,
                                       const unsigned short* hA, int mtb,
                                       const int (&rowb)[8], int lane, int quad)
{
    #pragma unroll
    for (int kk = 0; kk < 4; ++kk) {
        bf16x8 a0 = *(const bf16x8*)&hA[(((mtb + 0) * 4 + kk) * 64 + lane) * 8];
        bf16x8 a1 = *(const bf16x8*)&hA[(((mtb + 1) * 4 + kk) * 64 + lane) * 8];
        #pragma unroll
        for (int ti = 0; ti < 8; ++ti) {
            bf16x8 b = *(const bf16x8*)&Wb[(size_t)rowb[ti] * 128 + kk * 32 + quad * 8];
            acc[0][ti] = __builtin_amdgcn_mfma_f32_16x16x32_bf16(a0, b, acc[0][ti], 0, 0, 0);
            acc[1][ti] = __builtin_amdgcn_mfma_f32_16x16x32_bf16(a1, b, acc[1][ti], 0, 0, 0);
        }
    }
}

__global__ __launch_bounds__(TPB, 2)
void lstm_mlp_mfma(const float* __restrict__ tfeat,
                   const float* __restrict__ Wih0,
                   const float* __restrict__ bih0, const float* __restrict__ bhh0,
                   const float* __restrict__ bih1, const float* __restrict__ bhh1,
                   const float* __restrict__ w0,  const float* __restrict__ b0,
                   const float* __restrict__ b1,
                   const unsigned short* __restrict__ wsb,
                   float* __restrict__ out)
{
    // LDS map (bytes): hA0 ping/pong [0,16K),[16K,32K); hA1 ping/pong [32K,48K),[48K,64K)
    // mhA aliases [0,32K) (dead hA0 pair); outb aliases [0,66560); xb/f3 live at the top.
    __shared__ __align__(16) char smem[70656];
    unsigned short* hA0b = (unsigned short*)smem;              // + pp*8192 shorts
    unsigned short* hA1b = (unsigned short*)(smem + 32768);    // + pp*8192 shorts
    unsigned short* mhA  = (unsigned short*)smem;
    float* outb = (float*)smem;                                // stride 260 floats
    float (*xb)[12] = (float(*)[12])(smem + 66560);
    float (*f3)[4]  = (float(*)[4])(smem + 69632);

    const int tid  = threadIdx.x;
    const int w8   = tid >> 6;      // 0..7
    const int ug   = w8 & 3;        // unit group (128 gate-rows per group)
    const int th   = w8 >> 2;       // track half (32 tracks)
    const int mtb  = th * 2;        // m-tile base (16-track tiles)
    const int lane = tid & 63;
    const int col  = lane & 15;
    const int quad = lane >> 4;
    const int base = blockIdx.x * MTRK;

    // ---- stage per-track inputs ----
    for (int idx = tid; idx < MTRK * 12; idx += TPB) {
        int tl = idx & 63, f = idx >> 6;
        int n = base + tl, b = n / NTRK, tt = n - b * NTRK;
        xb[tl][f] = tfeat[(size_t)(b * 18 + 6 + f) * NTRK + tt];
    }
    for (int idx = tid; idx < MTRK * 3; idx += TPB) {
        int tl = idx & 63, f = idx >> 6;
        int n = base + tl, b = n / NTRK, tt = n - b * NTRK;
        f3[tl][f] = tfeat[(size_t)(b * 18 + f) * NTRK + tt];
    }
    __syncthreads();

    const unsigned short* Whh0b = wsb + WHH0_OFF;
    const unsigned short* Wih1b = wsb + WIH1_OFF;
    const unsigned short* Whh1b = wsb + WHH1_OFF;
    const unsigned short* w0b   = wsb + W0B_OFF;
    const unsigned short* w1b   = wsb + W1B_OFF;

    // ---- hoisted per-tile constants (t-invariant) ----
    int   rowg[8];
    float bs0[8], bs1[8], wx0[8], wx1[8];
    #pragma unroll
    for (int ti = 0; ti < 8; ++ti) {
        int g = ti >> 1, p = ti & 1;
        int n = g * 128 + ug * 32 + p * 16 + col;
        rowg[ti] = n;
        bs0[ti] = bih0[n] + bhh0[n];
        bs1[ti] = bih1[n] + bhh1[n];
        wx0[ti] = Wih0[2 * n];
        wx1[ti] = Wih0[2 * n + 1];
    }

    f32x4 c0[2][2], c1[2][2];
    #pragma unroll
    for (int mt = 0; mt < 2; ++mt)
        #pragma unroll
        for (int p = 0; p < 2; ++p)
            #pragma unroll
            for (int r = 0; r < 4; ++r) { c0[mt][p][r] = 0.0f; c1[mt][p][r] = 0.0f; }

    for (int t = 0; t < TSTEPS; ++t) {
        const int rb = t & 1, wb = rb ^ 1;
        unsigned short* hA0r = hA0b + rb * 8192;
        unsigned short* hA0w = hA0b + wb * 8192;
        unsigned short* hA1r = hA1b + rb * 8192;
        unsigned short* hA1w = hA1b + wb * 8192;
        f32x4 acc[2][8];

        // ---------- layer 0: reads hA0r, writes hA0w (ping-pong, no WAR barrier) ----------
        #pragma unroll
        for (int mt = 0; mt < 2; ++mt)
            #pragma unroll
            for (int ti = 0; ti < 8; ++ti)
                #pragma unroll
                for (int r = 0; r < 4; ++r) {
                    int m = th * 32 + mt * 16 + quad * 4 + r;
                    acc[mt][ti][r] = bs0[ti] + xb[m][2 * t] * wx0[ti] + xb[m][2 * t + 1] * wx1[ti];
                }
        if (t > 0) accum8(acc, Whh0b, hA0r, mtb, rowg, lane, quad);
        #pragma unroll
        for (int mt = 0; mt < 2; ++mt)
            #pragma unroll
            for (int p = 0; p < 2; ++p)
                #pragma unroll
                for (int r = 0; r < 4; ++r) {
                    float iv = sigf(acc[mt][0 + p][r]);
                    float fv = sigf(acc[mt][2 + p][r]);
                    float gv = tanhfast(acc[mt][4 + p][r]);
                    float ov = sigf(acc[mt][6 + p][r]);
                    float cn = fv * c0[mt][p][r] + iv * gv;
                    c0[mt][p][r] = cn;
                    int m = th * 32 + mt * 16 + quad * 4 + r;
                    int u = ug * 32 + p * 16 + col;
                    hA0w[aoff4(m, u)] = f2b(ov * tanhfast(cn));
                }
        __syncthreads();   // single barrier per t: publish h0[t]; orders all cross-step hazards

        // ---------- layer 1: reads hA0w (new h0) + hA1r, writes hA1w ----------
        #pragma unroll
        for (int mt = 0; mt < 2; ++mt)
            #pragma unroll
            for (int ti = 0; ti < 8; ++ti)
                #pragma unroll
                for (int r = 0; r < 4; ++r) acc[mt][ti][r] = bs1[ti];
        accum8(acc, Wih1b, hA0w, mtb, rowg, lane, quad);
        if (t > 0) accum8(acc, Whh1b, hA1r, mtb, rowg, lane, quad);
        #pragma unroll
        for (int mt = 0; mt < 2; ++mt)
            #pragma unroll
            for (int p = 0; p < 2; ++p)
                #pragma unroll
                for (int r = 0; r < 4; ++r) {
                    float iv = sigf(acc[mt][0 + p][r]);
                    float fv = sigf(acc[mt][2 + p][r]);
                    float gv = tanhfast(acc[mt][4 + p][r]);
                    float ov = sigf(acc[mt][6 + p][r]);
                    float cn = fv * c1[mt][p][r] + iv * gv;
                    c1[mt][p][r] = cn;
                    int m = th * 32 + mt * 16 + quad * 4 + r;
                    int u = ug * 32 + p * 16 + col;
                    hA1w[aoff4(m, u)] = f2b(ov * tanhfast(cn));
                }
        // no trailing barrier: next t's barrier (after L0) orders L1(t)->L1(t+1)
    }
    __syncthreads();       // publish final h1 (TSTEPS=6 -> final write buffer index 0)
    const unsigned short* hF = hA1b;   // wb at t=5 is 0

    // ---------- MLP layer A: mh = relu([f3, h1] @ w0^T + b0) ----------
    {
        f32x4 am[2][4];
        int rowm[4];
        #pragma unroll
        for (int ti = 0; ti < 4; ++ti) {
            int n = ug * 64 + ti * 16 + col;
            rowm[ti] = n;
            float bm  = b0[n];
            float wf0 = w0[n * 131 + 0], wf1 = w0[n * 131 + 1], wf2 = w0[n * 131 + 2];
            #pragma unroll
            for (int mt = 0; mt < 2; ++mt)
                #pragma unroll
                for (int r = 0; r < 4; ++r) {
                    int m = th * 32 + mt * 16 + quad * 4 + r;
                    am[mt][ti][r] = bm + f3[m][0] * wf0 + f3[m][1] * wf1 + f3[m][2] * wf2;
                }
        }
        #pragma unroll
        for (int kk = 0; kk < 4; ++kk) {
            bf16x8 a0 = *(const bf16x8*)&hF[(((mtb + 0) * 4 + kk) * 64 + lane) * 8];
            bf16x8 a1 = *(const bf16x8*)&hF[(((mtb + 1) * 4 + kk) * 64 + lane) * 8];
            #pragma unroll
            for (int ti = 0; ti < 4; ++ti) {
                bf16x8 b = *(const bf16x8*)&w0b[(size_t)rowm[ti] * 128 + kk * 32 + quad * 8];
                am[0][ti] = __builtin_amdgcn_mfma_f32_16x16x32_bf16(a0, b, am[0][ti], 0, 0, 0);
                am[1][ti] = __builtin_amdgcn_mfma_f32_16x16x32_bf16(a1, b, am[1][ti], 0, 0, 0);
            }
        }
        // mhA aliases dead hA0 pair [0,32K): safe, hF is at [32K,48K)
        #pragma unroll
        for (int mt = 0; mt < 2; ++mt)
            #pragma unroll
            for (int ti = 0; ti < 4; ++ti)
                #pragma unroll
                for (int r = 0; r < 4; ++r) {
                    int m = th * 32 + mt * 16 + quad * 4 + r;
                    int u = ug * 64 + ti * 16 + col;
                    int off = (((m >> 4) * 8 + (u >> 5)) * 64 + ((u >> 3) & 3) * 16 + (m & 15)) * 8 + (u & 7);
                    mhA[off] = f2b(fmaxf(am[mt][ti][r], 0.0f));
                }
        __syncthreads();
    }

    // ---------- MLP layer B: out = mh @ w1^T + b1 ----------
    {
        f32x4 ao[2][4];
        int rowm[4];
        #pragma unroll
        for (int ti = 0; ti < 4; ++ti) {
            int n = ug * 64 + ti * 16 + col;
            rowm[ti] = n;
            float bv = b1[n];
            #pragma unroll
            for (int mt = 0; mt < 2; ++mt)
                #pragma unroll
                for (int r = 0; r < 4; ++r) ao[mt][ti][r] = bv;
        }
        #pragma unroll
        for (int kk = 0; kk < 8; ++kk) {
            bf16x8 a0 = *(const bf16x8*)&mhA[(((mtb + 0) * 8 + kk) * 64 + lane) * 8];
            bf16x8 a1 = *(const bf16x8*)&mhA[(((mtb + 1) * 8 + kk) * 64 + lane) * 8];
            #pragma unroll
            for (int ti = 0; ti < 4; ++ti) {
                bf16x8 b = *(const bf16x8*)&w1b[(size_t)rowm[ti] * 256 + kk * 32 + quad * 8];
                ao[0][ti] = __builtin_amdgcn_mfma_f32_16x16x32_bf16(a0, b, ao[0][ti], 0, 0, 0);
                ao[1][ti] = __builtin_amdgcn_mfma_f32_16x16x32_bf16(a1, b, ao[1][ti], 0, 0, 0);
            }
        }
        __syncthreads();   // all mhA reads complete; LDS reusable as outb

        #pragma unroll
        for (int mt = 0; mt < 2; ++mt)
            #pragma unroll
            for (int ti = 0; ti < 4; ++ti)
                #pragma unroll
                for (int r = 0; r < 4; ++r)
                    outb[(th * 32 + mt * 16 + quad * 4 + r) * 260 + ug * 64 + ti * 16 + col] = ao[mt][ti][r];
        __syncthreads();

        // fully-coalesced stores: 16 B/lane
        for (int i = tid; i < MTRK * 64; i += TPB) {
            int row = i >> 6, c4 = (i & 63) << 2;
            f32x4 v = *(const f32x4*)&outb[row * 260 + c4];
            __builtin_nontemporal_store(v, (f32x4*)(out + (size_t)(base + row) * HID + c4));
        }
    }
}

// pos_encoding + logpt/eta/phi passthrough.
__global__ __launch_bounds__(256)
void pos_kernel(const float* __restrict__ tfeat, float* __restrict__ out)
{
    const int idx = blockIdx.x * 256 + threadIdx.x;   // NTOT*32 threads
    const int m = idx & 31;
    const int n = idx >> 5;
    const int b = n / NTRK, tt = n - b * NTRK;

    const float eta = tfeat[(size_t)(b * 18 + 3) * NTRK + tt];
    const float phi = tfeat[(size_t)(b * 18 + 4) * NTRK + tt];

    // 10000^(-m/32) = exp2(-m * log2(10000)/32)
    const float inv = exp2f(-(float)m * (13.28771237954945f / 32.0f));
    const float TWO_PI = 6.28318530717958647692f;
    const float pe = eta * TWO_PI * inv;
    const float pp = phi * TWO_PI * inv;

    float* o1 = out + OUT1_OFF + (size_t)n * (HID / 2);
    __builtin_nontemporal_store(sinf(pe), o1 + 2 * m);
    __builtin_nontemporal_store(cosf(pe), o1 + 2 * m + 1);
    __builtin_nontemporal_store(sinf(pp), o1 + 64 + 2 * m);
    __builtin_nontemporal_store(cosf(pp), o1 + 64 + 2 * m + 1);

    if (m == 0) {
        __builtin_nontemporal_store(tfeat[(size_t)(b * 18 + 2) * NTRK + tt], out + OUT2_OFF + n);
        __builtin_nontemporal_store(eta, out + OUT3_OFF + n);
        __builtin_nontemporal_store(phi, out + OUT4_OFF + n);
    }
}

extern "C" void kernel_launch(void* const* d_in, const int* in_sizes, int n_in,
                              void* d_out, int out_size, void* d_ws, size_t ws_size,
                              hipStream_t stream)
{
    const float* tfeat = (const float*)d_in[0];
    const float* Wih0  = (const float*)d_in[1];
    const float* Whh0  = (const float*)d_in[2];
    const float* bih0  = (const float*)d_in[3];
    const float* bhh0  = (const float*)d_in[4];
    const float* Wih1  = (const float*)d_in[5];
    const float* Whh1  = (const float*)d_in[6];
    const float* bih1  = (const float*)d_in[7];
    const float* bhh1  = (const float*)d_in[8];
    const float* w0    = (const float*)d_in[9];
    const float* b0    = (const float*)d_in[10];
    const float* w1    = (const float*)d_in[11];
    const float* b1    = (const float*)d_in[12];
    float* out = (float*)d_out;
    unsigned short* wsb = (unsigned short*)d_ws;  // 576 KiB bf16 weights

    hipLaunchKernelGGL(prep_kernel, dim3((WS_SHORTS + 255) / 256), dim3(256), 0, stream,
                       Whh0, Wih1, Whh1, w0, w1, wsb);
    hipLaunchKernelGGL(lstm_mlp_mfma, dim3(NBLK), dim3(TPB), 0, stream,
                       tfeat, Wih0, bih0, bhh0, bih1, bhh1, w0, b0, b1, wsb, out);
    hipLaunchKernelGGL(pos_kernel, dim3((NTOT * 32) / 256), dim3(256), 0, stream,
                       tfeat, out);
}